// Round 7
// baseline (200.352 us; speedup 1.0000x reference)
//
#include <hip/hip_runtime.h>

typedef __attribute__((ext_vector_type(8))) short short8;
typedef __attribute__((ext_vector_type(4))) short short4v;
typedef __attribute__((ext_vector_type(4))) float float4v;

#define MFMA16(a, b, c) __builtin_amdgcn_mfma_f32_16x16x32_bf16((a), (b), (c), 0, 0, 0)

constexpr int kThreads = 512;
// LDS (ushort units):
//   [0,     32768)  K2 : pos-major; 8 granules of 16B per pos-row.
//                   granule g = cp*4+quad (XOR pos&7); content
//                   [K[pos][cp*32+quad*4+0..3], K[pos][cp*32+16+quad*4+0..3]]
//   [32768, 65536)  V2 : d-major; granule [qg][kp] with kp-field XOR (d&7) XOR qg;
//                   content [V[kp*32+qg*4+0..3][d], V[kp*32+16+qg*4+0..3][d]]
//   [65536, 77824)  Wq^T/Wk^T/Wv^T staging (3 x 4096), 8-consecutive-d b128 frags
//   [77824, 81920)  Wd2 : e-major; granule g = cp*4+quad (XOR e&7)
constexpr int LDS_TOTAL_BYTES = 163840;  // 160 KiB -> 1 block/CU
// NOTE: 1 block/CU => 2 waves/SIMD => hard budget 256 unified VGPR+AGPR/wave.
// Full-S (s[32]) spilled ~12KB/thread; online softmax (s[8] chunks) fits, and
// leaves room for the 2-q-tile phase-2 below (~190 live regs peak).

static __device__ __forceinline__ unsigned short f2bf(float f) {
  // round-to-nearest-even fp32 -> bf16
  unsigned int u = __float_as_uint(f);
  u = (u + 0x7fffu + ((u >> 16) & 1u)) >> 16;
  return (unsigned short)u;
}

// W^T staging swizzle for phase 1 (b128 frags of 8 consecutive d).
static __device__ __forceinline__ int wsw_idx(int e, int d) {
  return ((((d >> 3) << 9) + (e << 3) + (d & 7)) ^ (((d >> 3) & 3) << 3));
}

__global__ __launch_bounds__(kThreads, 2) void ts_attn_fused(
    const float* __restrict__ x, const float* __restrict__ Wq_t,
    const float* __restrict__ Wk_t, const float* __restrict__ Wv_t,
    const float* __restrict__ Wq_s, const float* __restrict__ Wk_s,
    const float* __restrict__ Wv_s, const float* __restrict__ Wd_t,
    const float* __restrict__ bd_t, const float* __restrict__ Wd_s,
    const float* __restrict__ bd_s, float* __restrict__ out,
    unsigned short* __restrict__ qws) {
  extern __shared__ __align__(16) unsigned short smem[];
  unsigned short* Ksw = smem;            // 32768 us
  unsigned short* Vsw = smem + 32768;    // 32768 us
  unsigned short* Wst = smem + 65536;    // 12288 us (3 x 4096)
  unsigned short* Wdsw = smem + 77824;   // 4096 us

  const int tid = threadIdx.x;
  const int wv = tid >> 6;
  const int lane = tid & 63;
  const int ln = lane & 15;   // q position within 16-tile
  const int quad = lane >> 4;
  const int e8 = ln & 7;      // lane-constant XOR key (pos&7 / e&7 of this lane's rows)
  const int b = blockIdx.x;

  const float* xb = x + (size_t)b * (512 * 64);
  float* outb = out + (size_t)b * (512 * 64);
  unsigned short* qg = qws + (size_t)b * (512 * 64);  // Q bf16 in slot-group order

  // bias preload: epilogue lane covers channels e = nt*16 + quad*4 + r
  float4v bd4[4];
#pragma unroll
  for (int nt = 0; nt < 4; ++nt) {
    const float4v bt = *reinterpret_cast<const float4v*>(bd_t + nt * 16 + quad * 4);
    const float4v bs = *reinterpret_cast<const float4v*>(bd_s + nt * 16 + quad * 4);
    bd4[nt] = bt + bs;
  }

#pragma unroll 1
  for (int br = 0; br < 2; ++br) {
    const float* Wq = br ? Wq_s : Wq_t;
    const float* Wk = br ? Wk_s : Wk_t;
    const float* Wv = br ? Wv_s : Wv_t;
    const float* Wd = br ? Wd_s : Wd_t;

    // ---- stage weight matrices into LDS (bf16) ----
    {
      const int d = tid >> 3;        // 0..63
      const int e0 = (tid & 7) * 8;  // 0..56
      const float* srcs[3] = {Wq, Wk, Wv};
#pragma unroll
      for (int g = 0; g < 3; ++g) {
        const float4v u = *reinterpret_cast<const float4v*>(srcs[g] + d * 64 + e0);
        const float4v v = *reinterpret_cast<const float4v*>(srcs[g] + d * 64 + e0 + 4);
        unsigned short* dst = Wst + g * 4096;
#pragma unroll
        for (int i = 0; i < 4; ++i) dst[wsw_idx(e0 + i, d)] = f2bf(u[i]);
#pragma unroll
        for (int i = 0; i < 4; ++i) dst[wsw_idx(e0 + 4 + i, d)] = f2bf(v[i]);
      }
      // Wd -> Wd2 slot-group layout: d -> (cp, quad_g, h)
      const int cp_ = d >> 5;
      const int c = d & 31;
      const int qd_ = (c >> 2) & 3;
      const int h_ = ((c >> 4) << 2) | (c & 3);
      const int gbase = (cp_ * 4 + qd_);
      const float4v u = *reinterpret_cast<const float4v*>(Wd + d * 64 + e0);
      const float4v v = *reinterpret_cast<const float4v*>(Wd + d * 64 + e0 + 4);
#pragma unroll
      for (int i = 0; i < 4; ++i) {
        const int e = e0 + i;
        Wdsw[e * 64 + ((gbase ^ (e & 7)) << 3) + h_] = f2bf(u[i]);
      }
#pragma unroll
      for (int i = 0; i < 4; ++i) {
        const int e = e0 + 4 + i;
        Wdsw[e * 64 + ((gbase ^ (e & 7)) << 3) + h_] = f2bf(v[i]);
      }
    }
    __syncthreads();

    // ---- phase 1: Q^T,K^T,V^T = W^T @ X^T. Q -> global ws; K,V -> LDS ----
#pragma unroll 1
    for (int mi = 0; mi < 4; ++mi) {
      const int mrow = (wv + mi * 8) * 16 + ln;
      // V2 decomposition of this row's position (for g==2 writes)
      const int kpq = mrow >> 5;
      const int w5 = mrow & 31;
      const int jj = ((w5 >> 4) << 2) | (w5 & 3);
      const int qg2 = (w5 >> 2) & 3;
      short8 xa0, xa1;  // X^T B-frags (native 8-run: slot j -> d = cc*32 + quad*8 + j)
      {
        const float4v u0 = *reinterpret_cast<const float4v*>(xb + mrow * 64 + quad * 8);
        const float4v v0 = *reinterpret_cast<const float4v*>(xb + mrow * 64 + quad * 8 + 4);
        const float4v u1 = *reinterpret_cast<const float4v*>(xb + mrow * 64 + 32 + quad * 8);
        const float4v v1 = *reinterpret_cast<const float4v*>(xb + mrow * 64 + 32 + quad * 8 + 4);
#pragma unroll
        for (int i = 0; i < 4; ++i) {
          xa0[i] = (short)f2bf(u0[i]);
          xa0[4 + i] = (short)f2bf(v0[i]);
          xa1[i] = (short)f2bf(u1[i]);
          xa1[4 + i] = (short)f2bf(v1[i]);
        }
      }
#pragma unroll
      for (int g = 0; g < 3; ++g) {
        const unsigned short* Wg = Wst + g * 4096;
#pragma unroll
        for (int nt = 0; nt < 4; ++nt) {
          const short8 w0 = *reinterpret_cast<const short8*>(Wg + wsw_idx(nt * 16 + ln, quad * 8));
          const short8 w1 = *reinterpret_cast<const short8*>(Wg + wsw_idx(nt * 16 + ln, 32 + quad * 8));
          float4v acc = {0.f, 0.f, 0.f, 0.f};
          acc = MFMA16(w0, xa0, acc);
          acc = MFMA16(w1, xa1, acc);
          // D-frag: acc[r] = M[mrow][e = nt*16 + quad*4 + r]
          if (g == 0) {
            short4v pk;
#pragma unroll
            for (int r = 0; r < 4; ++r) pk[r] = (short)f2bf(acc[r]);
            *reinterpret_cast<short4v*>(
                qg + mrow * 64 + (nt >> 1) * 32 + quad * 8 + (nt & 1) * 4) = pk;
          } else if (g == 1) {
            short4v pk;
#pragma unroll
            for (int r = 0; r < 4; ++r) pk[r] = (short)f2bf(acc[r]);
            const int gswz = ((nt >> 1) * 4 + quad) ^ (mrow & 7);
            *reinterpret_cast<short4v*>(
                Ksw + mrow * 64 + (gswz << 3) + (nt & 1) * 4) = pk;
          } else {
            // V write: granule field XOR qg2 spreads the 16-lane store across
            // 4 bank-groups (was 8-way conflict in 2 banks without it).
#pragma unroll
            for (int r = 0; r < 4; ++r) {
              const int d = nt * 16 + quad * 4 + r;
              const int gv = (kpq ^ (d & 7) ^ qg2);
              Vsw[(d << 9) + (qg2 << 7) + (gv << 3) + jj] = f2bf(acc[r]);
            }
          }
        }
      }
    }
    __syncthreads();

    // ---- phase 2: TWO q-tiles per iteration (A: wv+qi*16, B: wv+8+qi*16) ----
    // Each K/V/Wd ds_read feeds both tiles -> LDS read volume halved; the two
    // independent softmax chains give the in-order wave ILP during lgkm waits.
#pragma unroll 1
    for (int qi = 0; qi < 2; ++qi) {
      const int qtA = wv + qi * 16;
      const int qtB = wv + 8 + qi * 16;
      const unsigned short* qrowA = qg + (qtA * 16 + ln) * 64;
      const unsigned short* qrowB = qg + (qtB * 16 + ln) * 64;
      const short8 qaA = *reinterpret_cast<const short8*>(qrowA + quad * 8);
      const short8 qbA = *reinterpret_cast<const short8*>(qrowA + 32 + quad * 8);
      const short8 qaB = *reinterpret_cast<const short8*>(qrowB + quad * 8);
      const short8 qbB = *reinterpret_cast<const short8*>(qrowB + 32 + quad * 8);

      const int kb0 = ln * 64 + ((quad ^ e8) << 3);        // cp=0 granule
      const int kb1 = ln * 64 + (((4 + quad) ^ e8) << 3);  // cp=1 granule
      const int vxor = (quad << 3) ^ (e8 << 3);            // V read granule XOR

      float4v oA[4], oB[4];
#pragma unroll
      for (int i = 0; i < 4; ++i) {
        oA[i] = (float4v){0.f, 0.f, 0.f, 0.f};
        oB[i] = (float4v){0.f, 0.f, 0.f, 0.f};
      }
      float mrunA = -3.0e38f, mrunB = -3.0e38f;
      float sumA = 0.f, sumB = 0.f;

#pragma unroll 1
      for (int ch = 0; ch < 4; ++ch) {
        // S chunks for both tiles: s*[k8][r], pos = (ch*8+k8)*16 + quad*4 + r
        float4v sA[8], sB[8];
#pragma unroll
        for (int k8 = 0; k8 < 8; ++k8) {
          const int kt = ch * 8 + k8;
          const short8 k0 = *reinterpret_cast<const short8*>(Ksw + kt * 1024 + kb0);
          const short8 k1 = *reinterpret_cast<const short8*>(Ksw + kt * 1024 + kb1);
          float4v aA = {0.f, 0.f, 0.f, 0.f};
          aA = MFMA16(k0, qaA, aA);
          aA = MFMA16(k1, qbA, aA);
          sA[k8] = aA;
          float4v aB = {0.f, 0.f, 0.f, 0.f};
          aB = MFMA16(k0, qaB, aB);
          aB = MFMA16(k1, qbB, aB);
          sB[k8] = aB;
        }

        // chunk max per tile (independent serial chains -> good dual issue)
        float4v m4A = sA[0], m4B = sB[0];
#pragma unroll
        for (int k8 = 1; k8 < 8; ++k8)
#pragma unroll
          for (int r = 0; r < 4; ++r) {
            m4A[r] = fmaxf(m4A[r], sA[k8][r]);
            m4B[r] = fmaxf(m4B[r], sB[k8][r]);
          }
        float cmxA = fmaxf(fmaxf(m4A[0], m4A[1]), fmaxf(m4A[2], m4A[3]));
        float cmxB = fmaxf(fmaxf(m4B[0], m4B[1]), fmaxf(m4B[2], m4B[3]));
        cmxA = fmaxf(cmxA, __shfl_xor(cmxA, 16, 64));
        cmxB = fmaxf(cmxB, __shfl_xor(cmxB, 16, 64));
        cmxA = fmaxf(cmxA, __shfl_xor(cmxA, 32, 64));
        cmxB = fmaxf(cmxB, __shfl_xor(cmxB, 32, 64));

        const float mnewA = fmaxf(mrunA, cmxA);
        const float mnewB = fmaxf(mrunB, cmxB);
        const float scaleA = __expf((mrunA - mnewA) * 0.125f);  // 0 on first chunk
        const float scaleB = __expf((mrunB - mnewB) * 0.125f);
        sumA *= scaleA;
        sumB *= scaleB;
#pragma unroll
        for (int i = 0; i < 4; ++i)
#pragma unroll
          for (int r = 0; r < 4; ++r) {
            oA[i][r] *= scaleA;
            oB[i][r] *= scaleB;
          }
        const float offsA = -mnewA * 0.125f;
        const float offsB = -mnewB * 0.125f;
        mrunA = mnewA;
        mrunB = mnewB;

        // exp -> pack -> PV (4 sub-chunks of 32 positions); V-frag shared A/B
#pragma unroll
        for (int kp = 0; kp < 4; ++kp) {
          float pA[8], pB[8];
#pragma unroll
          for (int h = 0; h < 2; ++h) {
            const int k8 = kp * 2 + h;
#pragma unroll
            for (int r = 0; r < 4; ++r) {
              pA[h * 4 + r] = __expf(fmaf(sA[k8][r], 0.125f, offsA));
              pB[h * 4 + r] = __expf(fmaf(sB[k8][r], 0.125f, offsB));
            }
          }
          sumA += ((pA[0] + pA[4]) + (pA[1] + pA[5])) + ((pA[2] + pA[6]) + (pA[3] + pA[7]));
          sumB += ((pB[0] + pB[4]) + (pB[1] + pB[5])) + ((pB[2] + pB[6]) + (pB[3] + pB[7]));
          short8 pfA, pfB;  // slot j -> pos = kpg*32 + (j>>2)*16 + quad*4 + (j&3)
#pragma unroll
          for (int j = 0; j < 8; ++j) {
            pfA[j] = (short)f2bf(pA[j]);
            pfB[j] = (short)f2bf(pB[j]);
          }
          const int kpg = ch * 4 + kp;
#pragma unroll
          for (int nto = 0; nto < 4; ++nto) {
            const int vb = (nto * 16 + ln) * 512 + quad * 128;
            const short8 vf = *reinterpret_cast<const short8*>(
                Vsw + vb + (((kpg << 3) ^ vxor)));
            oA[nto] = MFMA16(vf, pfA, oA[nto]);  // O^T[d=nto*16+quad*4+r][q=ln]
            oB[nto] = MFMA16(vf, pfB, oB[nto]);
          }
        }
      }

      sumA += __shfl_xor(sumA, 16, 64);
      sumB += __shfl_xor(sumB, 16, 64);
      sumA += __shfl_xor(sumA, 32, 64);
      sumB += __shfl_xor(sumB, 32, 64);
      const float invA = 1.0f / sumA;
      const float invB = 1.0f / sumB;

      // O^T -> bf16 B-frags
      short8 of0A, of1A, of0B, of1B;
#pragma unroll
      for (int r = 0; r < 4; ++r) {
        of0A[r] = (short)f2bf(oA[0][r] * invA);
        of0A[4 + r] = (short)f2bf(oA[1][r] * invA);
        of1A[r] = (short)f2bf(oA[2][r] * invA);
        of1A[4 + r] = (short)f2bf(oA[3][r] * invA);
        of0B[r] = (short)f2bf(oB[0][r] * invB);
        of0B[4 + r] = (short)f2bf(oB[1][r] * invB);
        of1B[r] = (short)f2bf(oB[2][r] * invB);
        of1B[4 + r] = (short)f2bf(oB[3][r] * invB);
      }

      // dense: Z^T = Wd^T @ O^T; Wd frags shared A/B; float4 epilogue
#pragma unroll
      for (int nt = 0; nt < 4; ++nt) {
        const int ebase = (nt * 16 + ln) * 64;
        const short8 w0 = *reinterpret_cast<const short8*>(
            Wdsw + ebase + ((quad ^ e8) << 3));
        const short8 w1 = *reinterpret_cast<const short8*>(
            Wdsw + ebase + (((4 + quad) ^ e8) << 3));
        float4v accA = {0.f, 0.f, 0.f, 0.f};
        accA = MFMA16(w0, of0A, accA);
        accA = MFMA16(w1, of1A, accA);
        float4v accB = {0.f, 0.f, 0.f, 0.f};
        accB = MFMA16(w0, of0B, accB);
        accB = MFMA16(w1, of1B, accB);
        const int e0 = nt * 16 + quad * 4;  // channel base (4 consecutive)
#pragma unroll
        for (int t = 0; t < 2; ++t) {
          const int row = (t == 0 ? qtA : qtB) * 16 + ln;
          const float4v acc = t == 0 ? accA : accB;
          float4v* op = reinterpret_cast<float4v*>(outb + row * 64 + e0);
          if (br == 0) {
            *op = acc;  // park temporal branch (sans bias)
          } else {
            const float4v parked = *op;
            const float4v xv = *reinterpret_cast<const float4v*>(xb + row * 64 + e0);
            float4v res;
#pragma unroll
            for (int r = 0; r < 4; ++r) {
              const float z = parked[r] + acc[r] + bd4[nt][r];
              const float gate = 1.0f / (1.0f + __expf(-z));
              res[r] = xv[r] * gate;
            }
            *op = res;
          }
        }
      }
    }
    __syncthreads();  // protect K/V/W LDS before next branch restages
  }
}

extern "C" void kernel_launch(void* const* d_in, const int* in_sizes, int n_in,
                              void* d_out, int out_size, void* d_ws, size_t ws_size,
                              hipStream_t stream) {
  const float* x = (const float*)d_in[0];
  const float* Wq_t = (const float*)d_in[1];
  const float* Wk_t = (const float*)d_in[2];
  const float* Wv_t = (const float*)d_in[3];
  const float* Wq_s = (const float*)d_in[4];
  const float* Wk_s = (const float*)d_in[5];
  const float* Wv_s = (const float*)d_in[6];
  const float* Wd_t = (const float*)d_in[7];
  const float* bd_t = (const float*)d_in[8];
  const float* Wd_s = (const float*)d_in[9];
  const float* bd_s = (const float*)d_in[10];
  float* out = (float*)d_out;
  unsigned short* qws = (unsigned short*)d_ws;  // 256*512*64*2 = 16 MiB

  hipFuncSetAttribute(reinterpret_cast<const void*>(ts_attn_fused),
                      hipFuncAttributeMaxDynamicSharedMemorySize, LDS_TOTAL_BYTES);
  ts_attn_fused<<<dim3(256), dim3(kThreads), LDS_TOTAL_BYTES, stream>>>(
      x, Wq_t, Wk_t, Wv_t, Wq_s, Wk_s, Wv_s, Wd_t, bd_t, Wd_s, bd_s, out, qws);
}

// Round 8
// 184.739 us; speedup vs baseline: 1.0845x; 1.0845x over previous
//
#include <hip/hip_runtime.h>

typedef __attribute__((ext_vector_type(8))) short short8;
typedef __attribute__((ext_vector_type(4))) short short4v;
typedef __attribute__((ext_vector_type(4))) float float4v;

#define MFMA16(a, b, c) __builtin_amdgcn_mfma_f32_16x16x32_bf16((a), (b), (c), 0, 0, 0)

constexpr int kThreads = 512;
// LDS (ushort units):
//   [0,     32768)  K2 : pos-major; 8 granules of 16B per pos-row.
//                   granule g = cp*4+quad (XOR pos&7); content
//                   [K[pos][cp*32+quad*4+0..3], K[pos][cp*32+16+quad*4+0..3]]
//   [32768, 65536)  V2 : d-major; granule [qg][kp] with kp-field XOR (d&7) XOR qg;
//                   content [V[kp*32+qg*4+0..3][d], V[kp*32+16+qg*4+0..3][d]]
//   [65536, 77824)  Wq^T/Wk^T/Wv^T staging (3 x 4096), 8-consecutive-d b128 frags
//   [77824, 81920)  Wd2 : e-major; granule g = cp*4+quad (XOR e&7)
constexpr int LDS_TOTAL_BYTES = 163840;  // 160 KiB -> 1 block/CU
// REGISTER BUDGET (hard-won): the allocator tops out at ~128 arch VGPRs here
// and spills to scratch instead of using the nominal 256 unified budget.
// r7 (peak live ~180: s-window 64) spilled ~500B/thread; r6 (~130) was clean.
// Keep peak live <= ~130: S-window = 4 tiles/tile-pair (32 regs), no long-held
// preloads (bias loaded in epilogue).

static __device__ __forceinline__ unsigned short f2bf(float f) {
  // round-to-nearest-even fp32 -> bf16
  unsigned int u = __float_as_uint(f);
  u = (u + 0x7fffu + ((u >> 16) & 1u)) >> 16;
  return (unsigned short)u;
}

// W^T staging swizzle for phase 1 (b128 frags of 8 consecutive d).
static __device__ __forceinline__ int wsw_idx(int e, int d) {
  return ((((d >> 3) << 9) + (e << 3) + (d & 7)) ^ (((d >> 3) & 3) << 3));
}

__global__ __launch_bounds__(kThreads, 2) void ts_attn_fused(
    const float* __restrict__ x, const float* __restrict__ Wq_t,
    const float* __restrict__ Wk_t, const float* __restrict__ Wv_t,
    const float* __restrict__ Wq_s, const float* __restrict__ Wk_s,
    const float* __restrict__ Wv_s, const float* __restrict__ Wd_t,
    const float* __restrict__ bd_t, const float* __restrict__ Wd_s,
    const float* __restrict__ bd_s, float* __restrict__ out,
    unsigned short* __restrict__ qws) {
  extern __shared__ __align__(16) unsigned short smem[];
  unsigned short* Ksw = smem;            // 32768 us
  unsigned short* Vsw = smem + 32768;    // 32768 us
  unsigned short* Wst = smem + 65536;    // 12288 us (3 x 4096)
  unsigned short* Wdsw = smem + 77824;   // 4096 us

  const int tid = threadIdx.x;
  const int wv = tid >> 6;
  const int lane = tid & 63;
  const int ln = lane & 15;   // q position within 16-tile
  const int quad = lane >> 4;
  const int e8 = ln & 7;      // lane-constant XOR key (pos&7 / e&7 of this lane's rows)
  const int b = blockIdx.x;

  const float* xb = x + (size_t)b * (512 * 64);
  float* outb = out + (size_t)b * (512 * 64);
  unsigned short* qg = qws + (size_t)b * (512 * 64);  // Q bf16 in slot-group order

#pragma unroll 1
  for (int br = 0; br < 2; ++br) {
    const float* Wq = br ? Wq_s : Wq_t;
    const float* Wk = br ? Wk_s : Wk_t;
    const float* Wv = br ? Wv_s : Wv_t;
    const float* Wd = br ? Wd_s : Wd_t;

    // ---- stage weight matrices into LDS (bf16) ----
    {
      const int d = tid >> 3;        // 0..63
      const int e0 = (tid & 7) * 8;  // 0..56
      const float* srcs[3] = {Wq, Wk, Wv};
#pragma unroll
      for (int g = 0; g < 3; ++g) {
        const float4v u = *reinterpret_cast<const float4v*>(srcs[g] + d * 64 + e0);
        const float4v v = *reinterpret_cast<const float4v*>(srcs[g] + d * 64 + e0 + 4);
        unsigned short* dst = Wst + g * 4096;
#pragma unroll
        for (int i = 0; i < 4; ++i) dst[wsw_idx(e0 + i, d)] = f2bf(u[i]);
#pragma unroll
        for (int i = 0; i < 4; ++i) dst[wsw_idx(e0 + 4 + i, d)] = f2bf(v[i]);
      }
      // Wd -> Wd2 slot-group layout: d -> (cp, quad_g, h)
      const int cp_ = d >> 5;
      const int c = d & 31;
      const int qd_ = (c >> 2) & 3;
      const int h_ = ((c >> 4) << 2) | (c & 3);
      const int gbase = (cp_ * 4 + qd_);
      const float4v u = *reinterpret_cast<const float4v*>(Wd + d * 64 + e0);
      const float4v v = *reinterpret_cast<const float4v*>(Wd + d * 64 + e0 + 4);
#pragma unroll
      for (int i = 0; i < 4; ++i) {
        const int e = e0 + i;
        Wdsw[e * 64 + ((gbase ^ (e & 7)) << 3) + h_] = f2bf(u[i]);
      }
#pragma unroll
      for (int i = 0; i < 4; ++i) {
        const int e = e0 + 4 + i;
        Wdsw[e * 64 + ((gbase ^ (e & 7)) << 3) + h_] = f2bf(v[i]);
      }
    }
    __syncthreads();

    // ---- phase 1: Q^T,K^T,V^T = W^T @ X^T. Q -> global ws; K,V -> LDS ----
#pragma unroll 1
    for (int mi = 0; mi < 4; ++mi) {
      const int mrow = (wv + mi * 8) * 16 + ln;
      // V2 decomposition of this row's position (for g==2 writes)
      const int kpq = mrow >> 5;
      const int w5 = mrow & 31;
      const int jj = ((w5 >> 4) << 2) | (w5 & 3);
      const int qg2 = (w5 >> 2) & 3;
      short8 xa0, xa1;  // X^T B-frags (native 8-run: slot j -> d = cc*32 + quad*8 + j)
      {
        const float4v u0 = *reinterpret_cast<const float4v*>(xb + mrow * 64 + quad * 8);
        const float4v v0 = *reinterpret_cast<const float4v*>(xb + mrow * 64 + quad * 8 + 4);
        const float4v u1 = *reinterpret_cast<const float4v*>(xb + mrow * 64 + 32 + quad * 8);
        const float4v v1 = *reinterpret_cast<const float4v*>(xb + mrow * 64 + 32 + quad * 8 + 4);
#pragma unroll
        for (int i = 0; i < 4; ++i) {
          xa0[i] = (short)f2bf(u0[i]);
          xa0[4 + i] = (short)f2bf(v0[i]);
          xa1[i] = (short)f2bf(u1[i]);
          xa1[4 + i] = (short)f2bf(v1[i]);
        }
      }
#pragma unroll
      for (int g = 0; g < 3; ++g) {
        const unsigned short* Wg = Wst + g * 4096;
#pragma unroll
        for (int nt = 0; nt < 4; ++nt) {
          const short8 w0 = *reinterpret_cast<const short8*>(Wg + wsw_idx(nt * 16 + ln, quad * 8));
          const short8 w1 = *reinterpret_cast<const short8*>(Wg + wsw_idx(nt * 16 + ln, 32 + quad * 8));
          float4v acc = {0.f, 0.f, 0.f, 0.f};
          acc = MFMA16(w0, xa0, acc);
          acc = MFMA16(w1, xa1, acc);
          // D-frag: acc[r] = M[mrow][e = nt*16 + quad*4 + r]
          if (g == 0) {
            short4v pk;
#pragma unroll
            for (int r = 0; r < 4; ++r) pk[r] = (short)f2bf(acc[r]);
            *reinterpret_cast<short4v*>(
                qg + mrow * 64 + (nt >> 1) * 32 + quad * 8 + (nt & 1) * 4) = pk;
          } else if (g == 1) {
            short4v pk;
#pragma unroll
            for (int r = 0; r < 4; ++r) pk[r] = (short)f2bf(acc[r]);
            const int gswz = ((nt >> 1) * 4 + quad) ^ (mrow & 7);
            *reinterpret_cast<short4v*>(
                Ksw + mrow * 64 + (gswz << 3) + (nt & 1) * 4) = pk;
          } else {
            // V write: granule field XOR qg2 spreads the 16-lane store across
            // 4 bank-groups (was 8-way conflict in 2 banks without it).
#pragma unroll
            for (int r = 0; r < 4; ++r) {
              const int d = nt * 16 + quad * 4 + r;
              const int gv = (kpq ^ (d & 7) ^ qg2);
              Vsw[(d << 9) + (qg2 << 7) + (gv << 3) + jj] = f2bf(acc[r]);
            }
          }
        }
      }
    }
    __syncthreads();

    // ---- phase 2: TWO q-tiles per iteration (A: wv+qi*16, B: wv+8+qi*16) ----
    // Each K/V/Wd ds_read feeds both tiles -> LDS read volume halved; the two
    // independent softmax chains give the in-order wave ILP during lgkm waits.
    // Online softmax window = 4 K-tiles (64 pos) -> sA[4]+sB[4] = 32 live regs.
#pragma unroll 1
    for (int qi = 0; qi < 2; ++qi) {
      const int qtA = wv + qi * 16;
      const int qtB = wv + 8 + qi * 16;
      const unsigned short* qrowA = qg + (qtA * 16 + ln) * 64;
      const unsigned short* qrowB = qg + (qtB * 16 + ln) * 64;
      const short8 qaA = *reinterpret_cast<const short8*>(qrowA + quad * 8);
      const short8 qbA = *reinterpret_cast<const short8*>(qrowA + 32 + quad * 8);
      const short8 qaB = *reinterpret_cast<const short8*>(qrowB + quad * 8);
      const short8 qbB = *reinterpret_cast<const short8*>(qrowB + 32 + quad * 8);

      const int kb0 = ln * 64 + ((quad ^ e8) << 3);        // cp=0 granule
      const int kb1 = ln * 64 + (((4 + quad) ^ e8) << 3);  // cp=1 granule
      const int vxor = (quad << 3) ^ (e8 << 3);            // V read granule XOR

      float4v oA[4], oB[4];
#pragma unroll
      for (int i = 0; i < 4; ++i) {
        oA[i] = (float4v){0.f, 0.f, 0.f, 0.f};
        oB[i] = (float4v){0.f, 0.f, 0.f, 0.f};
      }
      float mrunA = -3.0e38f, mrunB = -3.0e38f;
      float sumA = 0.f, sumB = 0.f;

#pragma unroll 1
      for (int ch = 0; ch < 8; ++ch) {
        // S chunks for both tiles: s*[k8][r], pos = (ch*4+k8)*16 + quad*4 + r
        float4v sA[4], sB[4];
#pragma unroll
        for (int k8 = 0; k8 < 4; ++k8) {
          const int kt = ch * 4 + k8;
          const short8 k0 = *reinterpret_cast<const short8*>(Ksw + kt * 1024 + kb0);
          const short8 k1 = *reinterpret_cast<const short8*>(Ksw + kt * 1024 + kb1);
          float4v aA = {0.f, 0.f, 0.f, 0.f};
          aA = MFMA16(k0, qaA, aA);
          aA = MFMA16(k1, qbA, aA);
          sA[k8] = aA;
          float4v aB = {0.f, 0.f, 0.f, 0.f};
          aB = MFMA16(k0, qaB, aB);
          aB = MFMA16(k1, qbB, aB);
          sB[k8] = aB;
        }

        // chunk max per tile (independent serial chains -> good dual issue)
        float4v m4A = sA[0], m4B = sB[0];
#pragma unroll
        for (int k8 = 1; k8 < 4; ++k8)
#pragma unroll
          for (int r = 0; r < 4; ++r) {
            m4A[r] = fmaxf(m4A[r], sA[k8][r]);
            m4B[r] = fmaxf(m4B[r], sB[k8][r]);
          }
        float cmxA = fmaxf(fmaxf(m4A[0], m4A[1]), fmaxf(m4A[2], m4A[3]));
        float cmxB = fmaxf(fmaxf(m4B[0], m4B[1]), fmaxf(m4B[2], m4B[3]));
        cmxA = fmaxf(cmxA, __shfl_xor(cmxA, 16, 64));
        cmxB = fmaxf(cmxB, __shfl_xor(cmxB, 16, 64));
        cmxA = fmaxf(cmxA, __shfl_xor(cmxA, 32, 64));
        cmxB = fmaxf(cmxB, __shfl_xor(cmxB, 32, 64));

        const float mnewA = fmaxf(mrunA, cmxA);
        const float mnewB = fmaxf(mrunB, cmxB);
        const float scaleA = __expf((mrunA - mnewA) * 0.125f);  // 0 on first chunk
        const float scaleB = __expf((mrunB - mnewB) * 0.125f);
        sumA *= scaleA;
        sumB *= scaleB;
#pragma unroll
        for (int i = 0; i < 4; ++i)
#pragma unroll
          for (int r = 0; r < 4; ++r) {
            oA[i][r] *= scaleA;
            oB[i][r] *= scaleB;
          }
        const float offsA = -mnewA * 0.125f;
        const float offsB = -mnewB * 0.125f;
        mrunA = mnewA;
        mrunB = mnewB;

        // exp -> pack -> PV (2 sub-chunks of 32 positions); V-frag shared A/B
#pragma unroll
        for (int kp = 0; kp < 2; ++kp) {
          float pA[8], pB[8];
#pragma unroll
          for (int h = 0; h < 2; ++h) {
            const int k8 = kp * 2 + h;
#pragma unroll
            for (int r = 0; r < 4; ++r) {
              pA[h * 4 + r] = __expf(fmaf(sA[k8][r], 0.125f, offsA));
              pB[h * 4 + r] = __expf(fmaf(sB[k8][r], 0.125f, offsB));
            }
          }
          sumA += ((pA[0] + pA[4]) + (pA[1] + pA[5])) + ((pA[2] + pA[6]) + (pA[3] + pA[7]));
          sumB += ((pB[0] + pB[4]) + (pB[1] + pB[5])) + ((pB[2] + pB[6]) + (pB[3] + pB[7]));
          short8 pfA, pfB;  // slot j -> pos = kpg*32 + (j>>2)*16 + quad*4 + (j&3)
#pragma unroll
          for (int j = 0; j < 8; ++j) {
            pfA[j] = (short)f2bf(pA[j]);
            pfB[j] = (short)f2bf(pB[j]);
          }
          const int kpg = ch * 2 + kp;
#pragma unroll
          for (int nto = 0; nto < 4; ++nto) {
            const int vb = (nto * 16 + ln) * 512 + quad * 128;
            const short8 vf = *reinterpret_cast<const short8*>(
                Vsw + vb + (((kpg << 3) ^ vxor)));
            oA[nto] = MFMA16(vf, pfA, oA[nto]);  // O^T[d=nto*16+quad*4+r][q=ln]
            oB[nto] = MFMA16(vf, pfB, oB[nto]);
          }
        }
      }

      sumA += __shfl_xor(sumA, 16, 64);
      sumB += __shfl_xor(sumB, 16, 64);
      sumA += __shfl_xor(sumA, 32, 64);
      sumB += __shfl_xor(sumB, 32, 64);
      const float invA = 1.0f / sumA;
      const float invB = 1.0f / sumB;

      // O^T -> bf16 B-frags
      short8 of0A, of1A, of0B, of1B;
#pragma unroll
      for (int r = 0; r < 4; ++r) {
        of0A[r] = (short)f2bf(oA[0][r] * invA);
        of0A[4 + r] = (short)f2bf(oA[1][r] * invA);
        of1A[r] = (short)f2bf(oA[2][r] * invA);
        of1A[4 + r] = (short)f2bf(oA[3][r] * invA);
        of0B[r] = (short)f2bf(oB[0][r] * invB);
        of0B[4 + r] = (short)f2bf(oB[1][r] * invB);
        of1B[r] = (short)f2bf(oB[2][r] * invB);
        of1B[4 + r] = (short)f2bf(oB[3][r] * invB);
      }

      // dense: Z^T = Wd^T @ O^T; Wd frags shared A/B; float4 epilogue
#pragma unroll
      for (int nt = 0; nt < 4; ++nt) {
        const int ebase = (nt * 16 + ln) * 64;
        const short8 w0 = *reinterpret_cast<const short8*>(
            Wdsw + ebase + ((quad ^ e8) << 3));
        const short8 w1 = *reinterpret_cast<const short8*>(
            Wdsw + ebase + (((4 + quad) ^ e8) << 3));
        float4v accA = {0.f, 0.f, 0.f, 0.f};
        accA = MFMA16(w0, of0A, accA);
        accA = MFMA16(w1, of1A, accA);
        float4v accB = {0.f, 0.f, 0.f, 0.f};
        accB = MFMA16(w0, of0B, accB);
        accB = MFMA16(w1, of1B, accB);
        const int e0 = nt * 16 + quad * 4;  // channel base (4 consecutive)
#pragma unroll
        for (int t = 0; t < 2; ++t) {
          const int row = (t == 0 ? qtA : qtB) * 16 + ln;
          const float4v acc = t == 0 ? accA : accB;
          float4v* op = reinterpret_cast<float4v*>(outb + row * 64 + e0);
          if (br == 0) {
            *op = acc;  // park temporal branch (sans bias)
          } else {
            // bias loaded here (L1-hot broadcast) instead of held in regs
            const float4v bt = *reinterpret_cast<const float4v*>(bd_t + e0);
            const float4v bs = *reinterpret_cast<const float4v*>(bd_s + e0);
            const float4v parked = *op;
            const float4v xv = *reinterpret_cast<const float4v*>(xb + row * 64 + e0);
            float4v res;
#pragma unroll
            for (int r = 0; r < 4; ++r) {
              const float z = parked[r] + acc[r] + bt[r] + bs[r];
              const float gate = 1.0f / (1.0f + __expf(-z));
              res[r] = xv[r] * gate;
            }
            *op = res;
          }
        }
      }
    }
    __syncthreads();  // protect K/V/W LDS before next branch restages
  }
}

extern "C" void kernel_launch(void* const* d_in, const int* in_sizes, int n_in,
                              void* d_out, int out_size, void* d_ws, size_t ws_size,
                              hipStream_t stream) {
  const float* x = (const float*)d_in[0];
  const float* Wq_t = (const float*)d_in[1];
  const float* Wk_t = (const float*)d_in[2];
  const float* Wv_t = (const float*)d_in[3];
  const float* Wq_s = (const float*)d_in[4];
  const float* Wk_s = (const float*)d_in[5];
  const float* Wv_s = (const float*)d_in[6];
  const float* Wd_t = (const float*)d_in[7];
  const float* bd_t = (const float*)d_in[8];
  const float* Wd_s = (const float*)d_in[9];
  const float* bd_s = (const float*)d_in[10];
  float* out = (float*)d_out;
  unsigned short* qws = (unsigned short*)d_ws;  // 256*512*64*2 = 16 MiB

  hipFuncSetAttribute(reinterpret_cast<const void*>(ts_attn_fused),
                      hipFuncAttributeMaxDynamicSharedMemorySize, LDS_TOTAL_BYTES);
  ts_attn_fused<<<dim3(256), dim3(kThreads), LDS_TOTAL_BYTES, stream>>>(
      x, Wq_t, Wk_t, Wv_t, Wq_s, Wk_s, Wv_s, Wd_t, bd_t, Wd_s, bd_s, out, qws);
}